// Round 12
// baseline (329.382 us; speedup 1.0000x reference)
//
#include <hip/hip_runtime.h>
#include <math.h>

// Problem constants
#define BSZ 4
#define NTOK 2048
#define CDIM 768
#define HN 8
#define DH 96
#define DP 32                 // D3
#define MTOT (BSZ * NTOK)     // 8192 tokens

typedef short bf16x8 __attribute__((ext_vector_type(8)));
typedef float f32x4 __attribute__((ext_vector_type(4)));

__device__ __forceinline__ unsigned short f2bf(float f) {
    union { float f; unsigned u; } v; v.f = f;
    unsigned r = v.u + 0x7FFFu + ((v.u >> 16) & 1u);   // RNE
    return (unsigned short)(r >> 16);
}
__device__ __forceinline__ unsigned short f2bf_trunc(float f) {
    union { float f; unsigned u; } v; v.f = f;
    return (unsigned short)(v.u >> 16);                // truncate (P>=0)
}
__device__ __forceinline__ float bf2f(unsigned short h) {
    union { unsigned u; float f; } v; v.u = ((unsigned)h) << 16;
    return v.f;
}

// async global->LDS, 16 B per lane: LDS dest = wave-uniform base + lane*16.
__device__ __forceinline__ void async16(const unsigned short* g, unsigned short* l) {
    __builtin_amdgcn_global_load_lds(
        (const __attribute__((address_space(1))) unsigned int*)g,
        (__attribute__((address_space(3))) unsigned int*)l,
        16, 0, 0);
}

// ---------------------------------------------------------------------------
// prep: one launch, pure bf16 converts (unchanged from round 9).
// ---------------------------------------------------------------------------
#define TE4 1572864   // TE/4
#define WE4 147456    // WE/4
#define WE24 768      // WE2/4

__global__ __launch_bounds__(256) void prep(const float* __restrict__ x,
                                            const float* __restrict__ Wqk,
                                            const float* __restrict__ Wv,
                                            const float* __restrict__ Wo,
                                            const float* __restrict__ We,
                                            const float* __restrict__ Wf,
                                            unsigned short* __restrict__ xhi,
                                            unsigned short* __restrict__ wqv,
                                            unsigned short* __restrict__ woh,
                                            unsigned short* __restrict__ webf,
                                            unsigned short* __restrict__ wfbf)
{
    int i = blockIdx.x * 256 + threadIdx.x;
    const float* src; unsigned short* dst; int j;
    if (i < TE4)                        { j = i;                        src = x;   dst = xhi; }
    else if (i < TE4 + WE4)             { j = i - TE4;                  src = Wqk; dst = wqv; }
    else if (i < TE4 + 2 * WE4)         { j = i - TE4 - WE4;            src = Wv;  dst = wqv + (size_t)CDIM * CDIM; }
    else if (i < TE4 + 3 * WE4)         { j = i - TE4 - 2 * WE4;        src = Wo;  dst = woh; }
    else if (i < TE4 + 3 * WE4 + WE24)  { j = i - TE4 - 3 * WE4;        src = We;  dst = webf; }
    else                                { j = i - TE4 - 3 * WE4 - WE24; src = Wf;  dst = wfbf; }
    float4 f = ((const float4*)src)[j];
    ushort4 u;
    u.x = f2bf(f.x); u.y = f2bf(f.y); u.z = f2bf(f.z); u.w = f2bf(f.w);
    ((ushort4*)dst)[j] = u;
}

// ---------------------------------------------------------------------------
// m97-style GEMM (unchanged from round 11): 128x128 tile, BK=32, XOR-swizzled
// async16 staging, single buffer, 2 barriers, 3 blocks/CU.
// ---------------------------------------------------------------------------
__global__ __launch_bounds__(256, 3) void gemm_qv(const unsigned short* __restrict__ Ah,
                                                  const unsigned short* __restrict__ wqv,
                                                  const float* __restrict__ bqk,
                                                  const float* __restrict__ bv,
                                                  unsigned short* __restrict__ qkbf,
                                                  unsigned short* __restrict__ vbf,
                                                  unsigned short* __restrict__ vbft)
{
    const int K = CDIM;
    __shared__ __align__(16) unsigned short As[8 * 512];
    __shared__ __align__(16) unsigned short Bs[8 * 512];

    const int tid  = threadIdx.x;
    const int lane = tid & 63;
    const int w    = tid >> 6;
    const int wy   = w >> 1;
    const int wx   = w & 1;
    const int l15  = lane & 15;
    const int quad = lane >> 4;
    const int n0   = blockIdx.x * 128;
    const int m0   = blockIdx.y * 128;

    const int srow   = lane >> 2;
    const int schunk = (lane & 3) ^ ((lane >> 3) & 3);
    const unsigned short* agp[2];
    const unsigned short* bgp[2];
    #pragma unroll
    for (int t = 0; t < 2; ++t) {
        int g = w * 2 + t;
        agp[t] = Ah  + (size_t)(m0 + g * 16 + srow) * K + schunk * 8;
        bgp[t] = wqv + (size_t)(n0 + g * 16 + srow) * K + schunk * 8;
    }

    const int roff = l15 * 32 + (quad ^ ((l15 >> 1) & 3)) * 8;

    f32x4 acc[4][4];
    #pragma unroll
    for (int rb = 0; rb < 4; ++rb)
        #pragma unroll
        for (int cb = 0; cb < 4; ++cb) acc[rb][cb] = (f32x4)0.0f;

    for (int k0 = 0; k0 < K; k0 += 32) {
        #pragma unroll
        for (int t = 0; t < 2; ++t) {
            async16(agp[t] + k0, &As[(w * 2 + t) * 512]);
            async16(bgp[t] + k0, &Bs[(w * 2 + t) * 512]);
        }
        __syncthreads();

        bf16x8 a[4], bfr[4];
        #pragma unroll
        for (int rb = 0; rb < 4; ++rb)
            a[rb] = *(const bf16x8*)&As[(wy * 4 + rb) * 512 + roff];
        #pragma unroll
        for (int cb = 0; cb < 4; ++cb)
            bfr[cb] = *(const bf16x8*)&Bs[(wx * 4 + cb) * 512 + roff];

        #pragma unroll
        for (int rb = 0; rb < 4; ++rb)
            #pragma unroll
            for (int cb = 0; cb < 4; ++cb)
                acc[rb][cb] = __builtin_amdgcn_mfma_f32_16x16x32_bf16(a[rb], bfr[cb], acc[rb][cb], 0, 0, 0);
        __syncthreads();
    }

    const bool isQ = (n0 < CDIM);
    #pragma unroll
    for (int rb = 0; rb < 4; ++rb)
        #pragma unroll
        for (int cb = 0; cb < 4; ++cb)
            #pragma unroll
            for (int r = 0; r < 4; ++r) {
                int row = m0 + wy * 64 + rb * 16 + quad * 4 + r;
                int colg = n0 + wx * 64 + cb * 16 + l15;
                if (isQ) {
                    float val = acc[rb][cb][r] + bqk[colg];
                    qkbf[(size_t)row * CDIM + colg] = f2bf(val);
                } else {
                    int col = colg - CDIM;
                    float val = acc[rb][cb][r] + bv[col];
                    vbf[(size_t)row * CDIM + col] = f2bf(val);
                    int b = row >> 11, tok = row & 2047;
                    int hh = col / DH, dd = col % DH;
                    vbft[(((size_t)b * HN + hh) * DH + dd) * NTOK + tok] = f2bf(val);
                }
            }
}

__global__ __launch_bounds__(256, 3) void gemm_out(const unsigned short* __restrict__ Ah,
                                                   const unsigned short* __restrict__ Bh,
                                                   const float* __restrict__ bias,
                                                   float* __restrict__ Yf)
{
    const int K = CDIM;
    __shared__ __align__(16) unsigned short As[8 * 512];
    __shared__ __align__(16) unsigned short Bs[8 * 512];

    const int tid  = threadIdx.x;
    const int lane = tid & 63;
    const int w    = tid >> 6;
    const int wy   = w >> 1;
    const int wx   = w & 1;
    const int l15  = lane & 15;
    const int quad = lane >> 4;
    const int n0   = blockIdx.x * 128;
    const int m0   = blockIdx.y * 128;

    const int srow   = lane >> 2;
    const int schunk = (lane & 3) ^ ((lane >> 3) & 3);
    const unsigned short* agp[2];
    const unsigned short* bgp[2];
    #pragma unroll
    for (int t = 0; t < 2; ++t) {
        int g = w * 2 + t;
        agp[t] = Ah + (size_t)(m0 + g * 16 + srow) * K + schunk * 8;
        bgp[t] = Bh + (size_t)(n0 + g * 16 + srow) * K + schunk * 8;
    }
    const int roff = l15 * 32 + (quad ^ ((l15 >> 1) & 3)) * 8;

    f32x4 acc[4][4];
    #pragma unroll
    for (int rb = 0; rb < 4; ++rb)
        #pragma unroll
        for (int cb = 0; cb < 4; ++cb) acc[rb][cb] = (f32x4)0.0f;

    for (int k0 = 0; k0 < K; k0 += 32) {
        #pragma unroll
        for (int t = 0; t < 2; ++t) {
            async16(agp[t] + k0, &As[(w * 2 + t) * 512]);
            async16(bgp[t] + k0, &Bs[(w * 2 + t) * 512]);
        }
        __syncthreads();

        bf16x8 a[4], bfr[4];
        #pragma unroll
        for (int rb = 0; rb < 4; ++rb)
            a[rb] = *(const bf16x8*)&As[(wy * 4 + rb) * 512 + roff];
        #pragma unroll
        for (int cb = 0; cb < 4; ++cb)
            bfr[cb] = *(const bf16x8*)&Bs[(wx * 4 + cb) * 512 + roff];

        #pragma unroll
        for (int rb = 0; rb < 4; ++rb)
            #pragma unroll
            for (int cb = 0; cb < 4; ++cb)
                acc[rb][cb] = __builtin_amdgcn_mfma_f32_16x16x32_bf16(a[rb], bfr[cb], acc[rb][cb], 0, 0, 0);
        __syncthreads();
    }

    #pragma unroll
    for (int rb = 0; rb < 4; ++rb)
        #pragma unroll
        for (int cb = 0; cb < 4; ++cb)
            #pragma unroll
            for (int r = 0; r < 4; ++r) {
                int row = m0 + wy * 64 + rb * 16 + quad * 4 + r;
                int col = n0 + wx * 64 + cb * 16 + l15;
                Yf[(size_t)row * CDIM + col] = 0.5f * acc[rb][cb][r] + bias[col];
            }
}

// ---------------------------------------------------------------------------
// Merged projection GEMM (unchanged).
// ---------------------------------------------------------------------------
#define PSTR 104

__global__ __launch_bounds__(256) void proj_gemm(const unsigned short* __restrict__ qkbf,
                                                 const unsigned short* __restrict__ vbf,
                                                 const unsigned short* __restrict__ webf,
                                                 const unsigned short* __restrict__ wfbf,
                                                 const float* __restrict__ be,
                                                 const float* __restrict__ bfv,
                                                 float* __restrict__ kp,
                                                 float* __restrict__ vp)
{
    const unsigned short* Abf = blockIdx.y ? vbf : qkbf;
    const unsigned short* Wbf = blockIdx.y ? wfbf : webf;
    const float* bias         = blockIdx.y ? bfv : be;
    float* Y                  = blockIdx.y ? vp : kp;

    __shared__ __align__(16) unsigned short As[128 * PSTR];
    __shared__ __align__(16) unsigned short Bs[32 * PSTR];

    const int tid  = threadIdx.x;
    const int lane = tid & 63;
    const int w    = tid >> 6;
    const int l15  = lane & 15;
    const int quad = lane >> 4;
    const int m0   = blockIdx.x * 128;

    {
        int r = tid & 127;
        int cb = (tid >> 7) * 12;
        #pragma unroll
        for (int t = 0; t < 12; ++t) {
            int c4 = cb + t;
            if (c4 < 24)
                *(ushort4*)&As[r * PSTR + c4 * 4] =
                    *(const ushort4*)&Abf[(size_t)(m0 + r) * DH + c4 * 4];
        }
    }
    #pragma unroll
    for (int t = 0; t < 3; ++t) {
        int idx = tid + t * 256;
        if (idx < 32 * 24) {
            int r = idx / 24, c4 = idx % 24;
            *(ushort4*)&Bs[r * PSTR + c4 * 4] = *(const ushort4*)&Wbf[r * DH + c4 * 4];
        }
    }
    __syncthreads();

    f32x4 acc[2][2];
    #pragma unroll
    for (int rb = 0; rb < 2; ++rb)
        #pragma unroll
        for (int cb = 0; cb < 2; ++cb) acc[rb][cb] = (f32x4)0.0f;

    #pragma unroll
    for (int kf = 0; kf < 3; ++kf) {
        bf16x8 a0 = *(const bf16x8*)&As[(w * 32 + l15) * PSTR + kf * 32 + quad * 8];
        bf16x8 a1 = *(const bf16x8*)&As[(w * 32 + 16 + l15) * PSTR + kf * 32 + quad * 8];
        bf16x8 b0 = *(const bf16x8*)&Bs[(l15) * PSTR + kf * 32 + quad * 8];
        bf16x8 b1 = *(const bf16x8*)&Bs[(16 + l15) * PSTR + kf * 32 + quad * 8];
        acc[0][0] = __builtin_amdgcn_mfma_f32_16x16x32_bf16(a0, b0, acc[0][0], 0, 0, 0);
        acc[0][1] = __builtin_amdgcn_mfma_f32_16x16x32_bf16(a0, b1, acc[0][1], 0, 0, 0);
        acc[1][0] = __builtin_amdgcn_mfma_f32_16x16x32_bf16(a1, b0, acc[1][0], 0, 0, 0);
        acc[1][1] = __builtin_amdgcn_mfma_f32_16x16x32_bf16(a1, b1, acc[1][1], 0, 0, 0);
    }

    #pragma unroll
    for (int rb = 0; rb < 2; ++rb)
        #pragma unroll
        for (int cb = 0; cb < 2; ++cb)
            #pragma unroll
            for (int r = 0; r < 4; ++r) {
                int row = m0 + w * 32 + rb * 16 + quad * 4 + r;
                int col = cb * 16 + l15;
                Y[(size_t)row * DP + col] = acc[rb][cb][r] + bias[col];
            }
}

// ---------------------------------------------------------------------------
// MFMA flash attention v5: QT=256 (grid 256, 1 block/CU). Wave owns 64 q-rows
// (4 rb) -> K/V LDS reads amortized over 2x the MFMA work vs QT=128 (the r11
// DS-read bottleneck). Staging/double-buffer/swizzle identical to v4.
// ---------------------------------------------------------------------------
#define QT 256
#define KT 32
#define PST 40
#define SCL2 0.14724420f   // (1/sqrt(96)) * log2(e)

__global__ __launch_bounds__(256, 1) void attn_mfma(const unsigned short* __restrict__ qk_bf,
                                                    const unsigned short* __restrict__ v_bft,
                                                    unsigned short* __restrict__ chi)
{
    __shared__ __align__(16) unsigned short KfS[2][6 * 512];   // 12288 B
    __shared__ __align__(16) unsigned short VfS[2][6 * 512];   // 12288 B
    __shared__ __align__(16) unsigned short Ps[QT * PST];      // 20480 B

    const int tid  = threadIdx.x;
    const int lane = tid & 63;
    const int w    = tid >> 6;       // wave 0..3, owns q-rows w*64..w*64+63
    const int l15  = lane & 15;
    const int quad = lane >> 4;

    // XCD swizzle: bid in [0,256): qt = bid>>5, bh = (bid&7)*4 + ((bid>>3)&3)
    const int bid = blockIdx.x;
    const int bh  = (bid & 7) * 4 + ((bid >> 3) & 3);
    const int qt  = bid >> 5;
    const int b   = bh >> 3;
    const int h   = bh & 7;
    const int q0  = qt * QT;

    const unsigned short* qbase = qk_bf + (size_t)b * NTOK * CDIM + h * DH;
    const unsigned short* vtb   = v_bft + (size_t)(b * HN + h) * DH * NTOK;

    // Q A-frags: 4 row-blocks of 16
    bf16x8 qf[4][3];
    #pragma unroll
    for (int rb = 0; rb < 4; ++rb)
        #pragma unroll
        for (int kf = 0; kf < 3; ++kf)
            qf[rb][kf] = *(const bf16x8*)&qbase[(size_t)(q0 + w * 64 + rb * 16 + l15) * CDIM + kf * 32 + quad * 8];

    const int  kjt   = w;                 // w<2: K jt
    const int  vd0   = (w - 2) * 3;       // w>=2: V chunk base
    const unsigned short* kgb = qbase + (size_t)(kjt * 16 + l15) * CDIM + quad * 8;
    const unsigned short* vgb = vtb + quad * 8;

    bf16x8 ones;
    #pragma unroll
    for (int i = 0; i < 8; ++i) ones[i] = (short)0x3F80;

    f32x4 o[4][6], ls[4];
    #pragma unroll
    for (int rb = 0; rb < 4; ++rb) {
        ls[rb] = (f32x4)0.0f;
        #pragma unroll
        for (int db = 0; db < 6; ++db) o[rb][db] = (f32x4)0.0f;
    }

    if (w < 2) {
        #pragma unroll
        for (int kf = 0; kf < 3; ++kf)
            async16(kgb + kf * 32, &KfS[0][(kf * 2 + kjt) * 512]);
    } else {
        #pragma unroll
        for (int t = 0; t < 3; ++t)
            async16(vgb + (size_t)((vd0 + t) * 16 + l15) * NTOK, &VfS[0][(vd0 + t) * 512]);
    }
    __syncthreads();

    int cur = 0;
    for (int k0 = 0; k0 < NTOK; k0 += KT) {
        const int nxt = cur ^ 1;
        if (k0 + KT < NTOK) {
            if (w < 2) {
                #pragma unroll
                for (int kf = 0; kf < 3; ++kf)
                    async16(kgb + (size_t)(k0 + KT) * CDIM + kf * 32, &KfS[nxt][(kf * 2 + kjt) * 512]);
            } else {
                #pragma unroll
                for (int t = 0; t < 3; ++t)
                    async16(vgb + (size_t)((vd0 + t) * 16 + l15) * NTOK + k0 + KT, &VfS[nxt][(vd0 + t) * 512]);
            }
        }

        // S = Q K^T for 4 row-blocks; K-frags read once, shared across rb
        f32x4 s0[4], s1[4];
        #pragma unroll
        for (int rb = 0; rb < 4; ++rb) { s0[rb] = (f32x4)0.0f; s1[rb] = (f32x4)0.0f; }
        #pragma unroll
        for (int kf = 0; kf < 3; ++kf) {
            bf16x8 k0f = *(const bf16x8*)&KfS[cur][(kf * 2 + 0) * 512 + lane * 8];
            bf16x8 k1f = *(const bf16x8*)&KfS[cur][(kf * 2 + 1) * 512 + lane * 8];
            #pragma unroll
            for (int rb = 0; rb < 4; ++rb) {
                s0[rb] = __builtin_amdgcn_mfma_f32_16x16x32_bf16(qf[rb][kf], k0f, s0[rb], 0, 0, 0);
                s1[rb] = __builtin_amdgcn_mfma_f32_16x16x32_bf16(qf[rb][kf], k1f, s1[rb], 0, 0, 0);
            }
        }

        // P = exp2(S*scale) -> LDS
        #pragma unroll
        for (int rb = 0; rb < 4; ++rb)
            #pragma unroll
            for (int r = 0; r < 4; ++r) {
                int prow = w * 64 + rb * 16 + quad * 4 + r;
                Ps[prow * PST + l15]      = f2bf_trunc(exp2f(s0[rb][r] * SCL2));
                Ps[prow * PST + l15 + 16] = f2bf_trunc(exp2f(s1[rb][r] * SCL2));
            }

        // O += P @ V ; l += P @ ones.  P-frags loaded once per rb; V-frags
        // loaded once per db and shared across all 4 rb.
        bf16x8 pf[4];
        #pragma unroll
        for (int rb = 0; rb < 4; ++rb) {
            pf[rb] = *(const bf16x8*)&Ps[(w * 64 + rb * 16 + l15) * PST + quad * 8];
            ls[rb] = __builtin_amdgcn_mfma_f32_16x16x32_bf16(pf[rb], ones, ls[rb], 0, 0, 0);
        }
        #pragma unroll
        for (int db = 0; db < 6; ++db) {
            bf16x8 vf = *(const bf16x8*)&VfS[cur][db * 512 + lane * 8];
            #pragma unroll
            for (int rb = 0; rb < 4; ++rb)
                o[rb][db] = __builtin_amdgcn_mfma_f32_16x16x32_bf16(pf[rb], vf, o[rb][db], 0, 0, 0);
        }

        __syncthreads();
        cur = nxt;
    }

    // epilogue: normalize, write out1 bf16
    #pragma unroll
    for (int rb = 0; rb < 4; ++rb)
        #pragma unroll
        for (int r = 0; r < 4; ++r) {
            float inv = 1.0f / ls[rb][r];
            int row = w * 64 + rb * 16 + quad * 4 + r;
            size_t base = ((size_t)b * NTOK + q0 + row) * CDIM + h * DH;
            #pragma unroll
            for (int db = 0; db < 6; ++db)
                chi[base + db * 16 + l15] = f2bf(o[rb][db][r] * inv);
        }
}

// ---------------------------------------------------------------------------
// Branch 2 (unchanged).
// ---------------------------------------------------------------------------
#define SFS 97

__global__ __launch_bounds__(256) void branch2_v2(const unsigned short* __restrict__ qkbf,
                                                  const float* __restrict__ kpG,
                                                  const float* __restrict__ vpG,
                                                  unsigned short* __restrict__ chi)
{
    __shared__ float qrowS[CDIM];
    __shared__ float SfS[DP * SFS];
    __shared__ float kpS[HN * DP];
    __shared__ float vpS[HN * DP];
    __shared__ float ps[DP][8];
    __shared__ float invs[DP];

    const int tid = threadIdx.x;
    const size_t tok = blockIdx.x;

    if (tid < 192) {
        ushort4 u = *(const ushort4*)&qkbf[tok * CDIM + tid * 4];
        float4 f;
        f.x = bf2f(u.x); f.y = bf2f(u.y); f.z = bf2f(u.z); f.w = bf2f(u.w);
        *(float4*)&qrowS[tid * 4] = f;
    } else {
        int t = tid - 192;
        ((float4*)kpS)[t] = ((const float4*)(kpG + tok * (HN * DP)))[t];
        ((float4*)vpS)[t] = ((const float4*)(vpG + tok * (HN * DP)))[t];
    }
    __syncthreads();

    #pragma unroll
    for (int t = 0; t < 12; ++t) {
        int idx = tid + t * 256;
        int e = idx / DH, d = idx % DH;
        float s = 0.0f;
        #pragma unroll
        for (int h = 0; h < HN; ++h) s += kpS[h * DP + e] * qrowS[h * DH + d];
        SfS[e * SFS + d] = exp2f(s * 1.44269504f);
    }
    __syncthreads();

    {
        int e = tid >> 3, g = tid & 7;
        float s = 0.0f;
        #pragma unroll
        for (int j = 0; j < 12; ++j) s += SfS[e * SFS + g * 12 + j];
        ps[e][g] = s;
    }
    __syncthreads();
    if (tid < DP) {
        float s = 0.0f;
        #pragma unroll
        for (int g = 0; g < 8; ++g) s += ps[tid][g];
        invs[tid] = 1.0f / s;
    }
    __syncthreads();
    {
        int h = tid >> 5, e = tid & 31;
        vpS[h * DP + e] *= invs[e];
    }
    __syncthreads();

    #pragma unroll
    for (int t = 0; t < 3; ++t) {
        int c = tid + t * 256;
        int h = c / DH, d = c % DH;
        float s = 0.0f;
        #pragma unroll 8
        for (int e = 0; e < DP; ++e) s += vpS[h * DP + e] * SfS[e * SFS + d];
        size_t idx = tok * CDIM + c;
        chi[idx] = f2bf(bf2f(chi[idx]) + s);
    }
}

// ---------------------------------------------------------------------------
// Launch pipeline (6 launches). Workspace ~82 MB.
// ---------------------------------------------------------------------------
extern "C" void kernel_launch(void* const* d_in, const int* in_sizes, int n_in,
                              void* d_out, int out_size, void* d_ws, size_t ws_size,
                              hipStream_t stream)
{
    (void)in_sizes; (void)n_in; (void)out_size; (void)ws_size;
    const float* x   = (const float*)d_in[0];
    const float* Wqk = (const float*)d_in[1];
    const float* bqk = (const float*)d_in[2];
    const float* Wv  = (const float*)d_in[3];
    const float* bv  = (const float*)d_in[4];
    const float* Wo  = (const float*)d_in[5];
    const float* bo  = (const float*)d_in[6];
    const float* We  = (const float*)d_in[7];
    const float* be  = (const float*)d_in[8];
    const float* Wf  = (const float*)d_in[9];
    const float* bfv = (const float*)d_in[10];
    float* out = (float*)d_out;

    const size_t TE  = (size_t)MTOT * CDIM;     // 6291456
    const size_t WE  = (size_t)CDIM * CDIM;     // 589824
    const size_t WE2 = (size_t)DP * DH;         // 3072
    const size_t PE  = (size_t)MTOT * HN * DP;  // 2097152

    char* p = (char*)d_ws;
    unsigned short* xhi  = (unsigned short*)p;   p += TE * 2;
    unsigned short* qkbf = (unsigned short*)p;   p += TE * 2;
    unsigned short* vbf  = (unsigned short*)p;   p += TE * 2;
    unsigned short* vbft = (unsigned short*)p;   p += TE * 2;
    unsigned short* chi  = (unsigned short*)p;   p += TE * 2;
    unsigned short* wqv  = (unsigned short*)p;   p += 2 * WE * 2;
    unsigned short* woh  = (unsigned short*)p;   p += WE * 2;
    unsigned short* webf = (unsigned short*)p;   p += WE2 * 2;
    unsigned short* wfbf = (unsigned short*)p;   p += WE2 * 2;
    float* kp            = (float*)p;            p += PE * 4;
    float* vp            = (float*)p;            p += PE * 4;

    const int prep_items = TE4 + 3 * WE4 + 2 * WE24;
    prep<<<dim3((prep_items + 255) / 256), 256, 0, stream>>>(
        x, Wqk, Wv, Wo, We, Wf, xhi, wqv, woh, webf, wfbf);

    gemm_qv<<<dim3(2 * CDIM / 128, MTOT / 128), 256, 0, stream>>>(
        xhi, wqv, bqk, bv, qkbf, vbf, vbft);

    proj_gemm<<<dim3(MTOT * HN / 128, 2), 256, 0, stream>>>(
        qkbf, vbf, webf, wfbf, be, bfv, kp, vp);

    attn_mfma<<<dim3((NTOK / QT) * BSZ * HN), 256, 0, stream>>>(qkbf, vbft, chi);

    branch2_v2<<<dim3(MTOT), 256, 0, stream>>>(qkbf, kp, vp, chi);

    gemm_out<<<dim3(CDIM / 128, MTOT / 128), 256, 0, stream>>>(chi, woh, bo, out);
}

// Round 13
// 287.906 us; speedup vs baseline: 1.1441x; 1.1441x over previous
//
#include <hip/hip_runtime.h>
#include <math.h>

// Problem constants
#define BSZ 4
#define NTOK 2048
#define CDIM 768
#define HN 8
#define DH 96
#define DP 32                 // D3
#define MTOT (BSZ * NTOK)     // 8192 tokens

typedef short bf16x8 __attribute__((ext_vector_type(8)));
typedef float f32x4 __attribute__((ext_vector_type(4)));

__device__ __forceinline__ unsigned short f2bf(float f) {
    union { float f; unsigned u; } v; v.f = f;
    unsigned r = v.u + 0x7FFFu + ((v.u >> 16) & 1u);   // RNE
    return (unsigned short)(r >> 16);
}
__device__ __forceinline__ unsigned short f2bf_trunc(float f) {
    union { float f; unsigned u; } v; v.f = f;
    return (unsigned short)(v.u >> 16);                // truncate (P>=0)
}
__device__ __forceinline__ float bf2f(unsigned short h) {
    union { unsigned u; float f; } v; v.u = ((unsigned)h) << 16;
    return v.f;
}

// async global->LDS, 16 B per lane: LDS dest = wave-uniform base + lane*16.
__device__ __forceinline__ void async16(const unsigned short* g, unsigned short* l) {
    __builtin_amdgcn_global_load_lds(
        (const __attribute__((address_space(1))) unsigned int*)g,
        (__attribute__((address_space(3))) unsigned int*)l,
        16, 0, 0);
}

// ---------------------------------------------------------------------------
// prep: one launch, pure bf16 converts.
// ---------------------------------------------------------------------------
#define TE4 1572864   // TE/4
#define WE4 147456    // WE/4
#define WE24 768      // WE2/4

__global__ __launch_bounds__(256) void prep(const float* __restrict__ x,
                                            const float* __restrict__ Wqk,
                                            const float* __restrict__ Wv,
                                            const float* __restrict__ Wo,
                                            const float* __restrict__ We,
                                            const float* __restrict__ Wf,
                                            unsigned short* __restrict__ xhi,
                                            unsigned short* __restrict__ wqv,
                                            unsigned short* __restrict__ woh,
                                            unsigned short* __restrict__ webf,
                                            unsigned short* __restrict__ wfbf)
{
    int i = blockIdx.x * 256 + threadIdx.x;
    const float* src; unsigned short* dst; int j;
    if (i < TE4)                        { j = i;                        src = x;   dst = xhi; }
    else if (i < TE4 + WE4)             { j = i - TE4;                  src = Wqk; dst = wqv; }
    else if (i < TE4 + 2 * WE4)         { j = i - TE4 - WE4;            src = Wv;  dst = wqv + (size_t)CDIM * CDIM; }
    else if (i < TE4 + 3 * WE4)         { j = i - TE4 - 2 * WE4;        src = Wo;  dst = woh; }
    else if (i < TE4 + 3 * WE4 + WE24)  { j = i - TE4 - 3 * WE4;        src = We;  dst = webf; }
    else                                { j = i - TE4 - 3 * WE4 - WE24; src = Wf;  dst = wfbf; }
    float4 f = ((const float4*)src)[j];
    ushort4 u;
    u.x = f2bf(f.x); u.y = f2bf(f.y); u.z = f2bf(f.z); u.w = f2bf(f.w);
    ((ushort4*)dst)[j] = u;
}

// ---------------------------------------------------------------------------
// m97-style GEMM (round 11 core). vbft scatter REMOVED from the epilogue
// (round-13 experiment: the [b,h,d,tok] store had lane-dim = d -> 4 KB
// stride -> 64 cache lines per store instruction; now done by transpose_v).
// ---------------------------------------------------------------------------
__global__ __launch_bounds__(256, 3) void gemm_qv(const unsigned short* __restrict__ Ah,
                                                  const unsigned short* __restrict__ wqv,
                                                  const float* __restrict__ bqk,
                                                  const float* __restrict__ bv,
                                                  unsigned short* __restrict__ qkbf,
                                                  unsigned short* __restrict__ vbf)
{
    const int K = CDIM;
    __shared__ __align__(16) unsigned short As[8 * 512];
    __shared__ __align__(16) unsigned short Bs[8 * 512];

    const int tid  = threadIdx.x;
    const int lane = tid & 63;
    const int w    = tid >> 6;
    const int wy   = w >> 1;
    const int wx   = w & 1;
    const int l15  = lane & 15;
    const int quad = lane >> 4;
    const int n0   = blockIdx.x * 128;
    const int m0   = blockIdx.y * 128;

    const int srow   = lane >> 2;
    const int schunk = (lane & 3) ^ ((lane >> 3) & 3);
    const unsigned short* agp[2];
    const unsigned short* bgp[2];
    #pragma unroll
    for (int t = 0; t < 2; ++t) {
        int g = w * 2 + t;
        agp[t] = Ah  + (size_t)(m0 + g * 16 + srow) * K + schunk * 8;
        bgp[t] = wqv + (size_t)(n0 + g * 16 + srow) * K + schunk * 8;
    }

    const int roff = l15 * 32 + (quad ^ ((l15 >> 1) & 3)) * 8;

    f32x4 acc[4][4];
    #pragma unroll
    for (int rb = 0; rb < 4; ++rb)
        #pragma unroll
        for (int cb = 0; cb < 4; ++cb) acc[rb][cb] = (f32x4)0.0f;

    for (int k0 = 0; k0 < K; k0 += 32) {
        #pragma unroll
        for (int t = 0; t < 2; ++t) {
            async16(agp[t] + k0, &As[(w * 2 + t) * 512]);
            async16(bgp[t] + k0, &Bs[(w * 2 + t) * 512]);
        }
        __syncthreads();

        bf16x8 a[4], bfr[4];
        #pragma unroll
        for (int rb = 0; rb < 4; ++rb)
            a[rb] = *(const bf16x8*)&As[(wy * 4 + rb) * 512 + roff];
        #pragma unroll
        for (int cb = 0; cb < 4; ++cb)
            bfr[cb] = *(const bf16x8*)&Bs[(wx * 4 + cb) * 512 + roff];

        #pragma unroll
        for (int rb = 0; rb < 4; ++rb)
            #pragma unroll
            for (int cb = 0; cb < 4; ++cb)
                acc[rb][cb] = __builtin_amdgcn_mfma_f32_16x16x32_bf16(a[rb], bfr[cb], acc[rb][cb], 0, 0, 0);
        __syncthreads();
    }

    const bool isQ = (n0 < CDIM);
    #pragma unroll
    for (int rb = 0; rb < 4; ++rb)
        #pragma unroll
        for (int cb = 0; cb < 4; ++cb)
            #pragma unroll
            for (int r = 0; r < 4; ++r) {
                int row = m0 + wy * 64 + rb * 16 + quad * 4 + r;
                int colg = n0 + wx * 64 + cb * 16 + l15;
                if (isQ) {
                    float val = acc[rb][cb][r] + bqk[colg];
                    qkbf[(size_t)row * CDIM + colg] = f2bf(val);
                } else {
                    int col = colg - CDIM;
                    float val = acc[rb][cb][r] + bv[col];
                    vbf[(size_t)row * CDIM + col] = f2bf(val);
                }
            }
}

// ---------------------------------------------------------------------------
// transpose_v: vbf [b*2048+tok][c] -> vbft [(b*768+c)*2048 + tok].
// 64x64 LDS tile (stride 66), coalesced ushort4 on both global sides.
// grid 4*384 = 1536 blocks.
// ---------------------------------------------------------------------------
__global__ __launch_bounds__(256) void transpose_v(const unsigned short* __restrict__ vbf,
                                                   unsigned short* __restrict__ vbft)
{
    __shared__ unsigned short T[64 * 66];
    const int tid   = threadIdx.x;
    const int chunk = tid & 15;        // 16 ushort4 chunks per 64-wide row
    const int r4    = tid >> 4;        // 0..15

    const int bt    = blockIdx.x;
    const int batch = bt / 384;
    const int rem   = bt % 384;
    const int tt    = rem / 12;        // tok tile 0..31
    const int ct    = rem % 12;        // c tile 0..11
    const int tok0  = tt * 64;
    const int c0    = ct * 64;

    const unsigned short* src = vbf + ((size_t)batch * NTOK + tok0) * CDIM + c0;
    #pragma unroll
    for (int p = 0; p < 4; ++p) {
        int r = r4 + p * 16;                       // tok within tile
        ushort4 v = *(const ushort4*)&src[(size_t)r * CDIM + chunk * 4];
        T[(chunk * 4 + 0) * 66 + r] = v.x;
        T[(chunk * 4 + 1) * 66 + r] = v.y;
        T[(chunk * 4 + 2) * 66 + r] = v.z;
        T[(chunk * 4 + 3) * 66 + r] = v.w;
    }
    __syncthreads();

    unsigned short* dst = vbft + ((size_t)batch * CDIM + c0) * NTOK + tok0;
    #pragma unroll
    for (int p = 0; p < 4; ++p) {
        int c = r4 + p * 16;                       // c within tile
        ushort4 v;
        v.x = T[c * 66 + chunk * 4 + 0];
        v.y = T[c * 66 + chunk * 4 + 1];
        v.z = T[c * 66 + chunk * 4 + 2];
        v.w = T[c * 66 + chunk * 4 + 3];
        *(ushort4*)&dst[(size_t)c * NTOK + chunk * 4] = v;
    }
}

// ---------------------------------------------------------------------------
// Final GEMM (round 11, unchanged).
// ---------------------------------------------------------------------------
__global__ __launch_bounds__(256, 3) void gemm_out(const unsigned short* __restrict__ Ah,
                                                   const unsigned short* __restrict__ Bh,
                                                   const float* __restrict__ bias,
                                                   float* __restrict__ Yf)
{
    const int K = CDIM;
    __shared__ __align__(16) unsigned short As[8 * 512];
    __shared__ __align__(16) unsigned short Bs[8 * 512];

    const int tid  = threadIdx.x;
    const int lane = tid & 63;
    const int w    = tid >> 6;
    const int wy   = w >> 1;
    const int wx   = w & 1;
    const int l15  = lane & 15;
    const int quad = lane >> 4;
    const int n0   = blockIdx.x * 128;
    const int m0   = blockIdx.y * 128;

    const int srow   = lane >> 2;
    const int schunk = (lane & 3) ^ ((lane >> 3) & 3);
    const unsigned short* agp[2];
    const unsigned short* bgp[2];
    #pragma unroll
    for (int t = 0; t < 2; ++t) {
        int g = w * 2 + t;
        agp[t] = Ah + (size_t)(m0 + g * 16 + srow) * K + schunk * 8;
        bgp[t] = Bh + (size_t)(n0 + g * 16 + srow) * K + schunk * 8;
    }
    const int roff = l15 * 32 + (quad ^ ((l15 >> 1) & 3)) * 8;

    f32x4 acc[4][4];
    #pragma unroll
    for (int rb = 0; rb < 4; ++rb)
        #pragma unroll
        for (int cb = 0; cb < 4; ++cb) acc[rb][cb] = (f32x4)0.0f;

    for (int k0 = 0; k0 < K; k0 += 32) {
        #pragma unroll
        for (int t = 0; t < 2; ++t) {
            async16(agp[t] + k0, &As[(w * 2 + t) * 512]);
            async16(bgp[t] + k0, &Bs[(w * 2 + t) * 512]);
        }
        __syncthreads();

        bf16x8 a[4], bfr[4];
        #pragma unroll
        for (int rb = 0; rb < 4; ++rb)
            a[rb] = *(const bf16x8*)&As[(wy * 4 + rb) * 512 + roff];
        #pragma unroll
        for (int cb = 0; cb < 4; ++cb)
            bfr[cb] = *(const bf16x8*)&Bs[(wx * 4 + cb) * 512 + roff];

        #pragma unroll
        for (int rb = 0; rb < 4; ++rb)
            #pragma unroll
            for (int cb = 0; cb < 4; ++cb)
                acc[rb][cb] = __builtin_amdgcn_mfma_f32_16x16x32_bf16(a[rb], bfr[cb], acc[rb][cb], 0, 0, 0);
        __syncthreads();
    }

    #pragma unroll
    for (int rb = 0; rb < 4; ++rb)
        #pragma unroll
        for (int cb = 0; cb < 4; ++cb)
            #pragma unroll
            for (int r = 0; r < 4; ++r) {
                int row = m0 + wy * 64 + rb * 16 + quad * 4 + r;
                int col = n0 + wx * 64 + cb * 16 + l15;
                Yf[(size_t)row * CDIM + col] = 0.5f * acc[rb][cb][r] + bias[col];
            }
}

// ---------------------------------------------------------------------------
// Merged projection GEMM (unchanged).
// ---------------------------------------------------------------------------
#define PSTR 104

__global__ __launch_bounds__(256) void proj_gemm(const unsigned short* __restrict__ qkbf,
                                                 const unsigned short* __restrict__ vbf,
                                                 const unsigned short* __restrict__ webf,
                                                 const unsigned short* __restrict__ wfbf,
                                                 const float* __restrict__ be,
                                                 const float* __restrict__ bfv,
                                                 float* __restrict__ kp,
                                                 float* __restrict__ vp)
{
    const unsigned short* Abf = blockIdx.y ? vbf : qkbf;
    const unsigned short* Wbf = blockIdx.y ? wfbf : webf;
    const float* bias         = blockIdx.y ? bfv : be;
    float* Y                  = blockIdx.y ? vp : kp;

    __shared__ __align__(16) unsigned short As[128 * PSTR];
    __shared__ __align__(16) unsigned short Bs[32 * PSTR];

    const int tid  = threadIdx.x;
    const int lane = tid & 63;
    const int w    = tid >> 6;
    const int l15  = lane & 15;
    const int quad = lane >> 4;
    const int m0   = blockIdx.x * 128;

    {
        int r = tid & 127;
        int cb = (tid >> 7) * 12;
        #pragma unroll
        for (int t = 0; t < 12; ++t) {
            int c4 = cb + t;
            if (c4 < 24)
                *(ushort4*)&As[r * PSTR + c4 * 4] =
                    *(const ushort4*)&Abf[(size_t)(m0 + r) * DH + c4 * 4];
        }
    }
    #pragma unroll
    for (int t = 0; t < 3; ++t) {
        int idx = tid + t * 256;
        if (idx < 32 * 24) {
            int r = idx / 24, c4 = idx % 24;
            *(ushort4*)&Bs[r * PSTR + c4 * 4] = *(const ushort4*)&Wbf[r * DH + c4 * 4];
        }
    }
    __syncthreads();

    f32x4 acc[2][2];
    #pragma unroll
    for (int rb = 0; rb < 2; ++rb)
        #pragma unroll
        for (int cb = 0; cb < 2; ++cb) acc[rb][cb] = (f32x4)0.0f;

    #pragma unroll
    for (int kf = 0; kf < 3; ++kf) {
        bf16x8 a0 = *(const bf16x8*)&As[(w * 32 + l15) * PSTR + kf * 32 + quad * 8];
        bf16x8 a1 = *(const bf16x8*)&As[(w * 32 + 16 + l15) * PSTR + kf * 32 + quad * 8];
        bf16x8 b0 = *(const bf16x8*)&Bs[(l15) * PSTR + kf * 32 + quad * 8];
        bf16x8 b1 = *(const bf16x8*)&Bs[(16 + l15) * PSTR + kf * 32 + quad * 8];
        acc[0][0] = __builtin_amdgcn_mfma_f32_16x16x32_bf16(a0, b0, acc[0][0], 0, 0, 0);
        acc[0][1] = __builtin_amdgcn_mfma_f32_16x16x32_bf16(a0, b1, acc[0][1], 0, 0, 0);
        acc[1][0] = __builtin_amdgcn_mfma_f32_16x16x32_bf16(a1, b0, acc[1][0], 0, 0, 0);
        acc[1][1] = __builtin_amdgcn_mfma_f32_16x16x32_bf16(a1, b1, acc[1][1], 0, 0, 0);
    }

    #pragma unroll
    for (int rb = 0; rb < 2; ++rb)
        #pragma unroll
        for (int cb = 0; cb < 2; ++cb)
            #pragma unroll
            for (int r = 0; r < 4; ++r) {
                int row = m0 + w * 32 + rb * 16 + quad * 4 + r;
                int col = cb * 16 + l15;
                Y[(size_t)row * DP + col] = acc[rb][cb][r] + bias[col];
            }
}

// ---------------------------------------------------------------------------
// MFMA flash attention v4 (round 11 version: QT=128, 2 blocks/CU).
// ---------------------------------------------------------------------------
#define QT 128
#define KT 32
#define PST 40
#define SCL2 0.14724420f   // (1/sqrt(96)) * log2(e)

__global__ __launch_bounds__(256) void attn_mfma(const unsigned short* __restrict__ qk_bf,
                                                 const unsigned short* __restrict__ v_bft,
                                                 unsigned short* __restrict__ chi)
{
    __shared__ __align__(16) unsigned short KfS[2][6 * 512];
    __shared__ __align__(16) unsigned short VfS[2][6 * 512];
    __shared__ __align__(16) unsigned short Ps[QT * PST];

    const int tid  = threadIdx.x;
    const int lane = tid & 63;
    const int w    = tid >> 6;
    const int l15  = lane & 15;
    const int quad = lane >> 4;

    const int bid = blockIdx.x;
    const int bh  = (bid & 7) * 4 + ((bid >> 3) & 3);
    const int qt  = bid >> 5;
    const int b   = bh >> 3;
    const int h   = bh & 7;
    const int q0  = qt * QT;

    const unsigned short* qbase = qk_bf + (size_t)b * NTOK * CDIM + h * DH;
    const unsigned short* vtb   = v_bft + (size_t)(b * HN + h) * DH * NTOK;

    bf16x8 qf[2][3];
    #pragma unroll
    for (int rb = 0; rb < 2; ++rb)
        #pragma unroll
        for (int kf = 0; kf < 3; ++kf)
            qf[rb][kf] = *(const bf16x8*)&qbase[(size_t)(q0 + w * 32 + rb * 16 + l15) * CDIM + kf * 32 + quad * 8];

    const int  kjt   = w;
    const int  vd0   = (w - 2) * 3;
    const unsigned short* kgb = qbase + (size_t)(kjt * 16 + l15) * CDIM + quad * 8;
    const unsigned short* vgb = vtb + quad * 8;

    bf16x8 ones;
    #pragma unroll
    for (int i = 0; i < 8; ++i) ones[i] = (short)0x3F80;

    f32x4 o[2][6], ls[2];
    #pragma unroll
    for (int rb = 0; rb < 2; ++rb) {
        ls[rb] = (f32x4)0.0f;
        #pragma unroll
        for (int db = 0; db < 6; ++db) o[rb][db] = (f32x4)0.0f;
    }

    if (w < 2) {
        #pragma unroll
        for (int kf = 0; kf < 3; ++kf)
            async16(kgb + kf * 32, &KfS[0][(kf * 2 + kjt) * 512]);
    } else {
        #pragma unroll
        for (int t = 0; t < 3; ++t)
            async16(vgb + (size_t)((vd0 + t) * 16 + l15) * NTOK, &VfS[0][(vd0 + t) * 512]);
    }
    __syncthreads();

    int cur = 0;
    for (int k0 = 0; k0 < NTOK; k0 += KT) {
        const int nxt = cur ^ 1;
        if (k0 + KT < NTOK) {
            if (w < 2) {
                #pragma unroll
                for (int kf = 0; kf < 3; ++kf)
                    async16(kgb + (size_t)(k0 + KT) * CDIM + kf * 32, &KfS[nxt][(kf * 2 + kjt) * 512]);
            } else {
                #pragma unroll
                for (int t = 0; t < 3; ++t)
                    async16(vgb + (size_t)((vd0 + t) * 16 + l15) * NTOK + k0 + KT, &VfS[nxt][(vd0 + t) * 512]);
            }
        }

        f32x4 s00 = (f32x4)0.0f, s01 = (f32x4)0.0f, s10 = (f32x4)0.0f, s11 = (f32x4)0.0f;
        #pragma unroll
        for (int kf = 0; kf < 3; ++kf) {
            bf16x8 k0f = *(const bf16x8*)&KfS[cur][(kf * 2 + 0) * 512 + lane * 8];
            bf16x8 k1f = *(const bf16x8*)&KfS[cur][(kf * 2 + 1) * 512 + lane * 8];
            s00 = __builtin_amdgcn_mfma_f32_16x16x32_bf16(qf[0][kf], k0f, s00, 0, 0, 0);
            s01 = __builtin_amdgcn_mfma_f32_16x16x32_bf16(qf[0][kf], k1f, s01, 0, 0, 0);
            s10 = __builtin_amdgcn_mfma_f32_16x16x32_bf16(qf[1][kf], k0f, s10, 0, 0, 0);
            s11 = __builtin_amdgcn_mfma_f32_16x16x32_bf16(qf[1][kf], k1f, s11, 0, 0, 0);
        }

        #pragma unroll
        for (int r = 0; r < 4; ++r) {
            int pr0 = w * 32 + quad * 4 + r;
            Ps[pr0 * PST + l15]      = f2bf_trunc(exp2f(s00[r] * SCL2));
            Ps[pr0 * PST + l15 + 16] = f2bf_trunc(exp2f(s01[r] * SCL2));
            int pr1 = pr0 + 16;
            Ps[pr1 * PST + l15]      = f2bf_trunc(exp2f(s10[r] * SCL2));
            Ps[pr1 * PST + l15 + 16] = f2bf_trunc(exp2f(s11[r] * SCL2));
        }

        bf16x8 pf0 = *(const bf16x8*)&Ps[(w * 32 + l15) * PST + quad * 8];
        bf16x8 pf1 = *(const bf16x8*)&Ps[(w * 32 + 16 + l15) * PST + quad * 8];
        ls[0] = __builtin_amdgcn_mfma_f32_16x16x32_bf16(pf0, ones, ls[0], 0, 0, 0);
        ls[1] = __builtin_amdgcn_mfma_f32_16x16x32_bf16(pf1, ones, ls[1], 0, 0, 0);
        #pragma unroll
        for (int db = 0; db < 6; ++db) {
            bf16x8 vf = *(const bf16x8*)&VfS[cur][db * 512 + lane * 8];
            o[0][db] = __builtin_amdgcn_mfma_f32_16x16x32_bf16(pf0, vf, o[0][db], 0, 0, 0);
            o[1][db] = __builtin_amdgcn_mfma_f32_16x16x32_bf16(pf1, vf, o[1][db], 0, 0, 0);
        }

        __syncthreads();
        cur = nxt;
    }

    #pragma unroll
    for (int rb = 0; rb < 2; ++rb)
        #pragma unroll
        for (int r = 0; r < 4; ++r) {
            float inv = 1.0f / ls[rb][r];
            int row = w * 32 + rb * 16 + quad * 4 + r;
            size_t base = ((size_t)b * NTOK + q0 + row) * CDIM + h * DH;
            #pragma unroll
            for (int db = 0; db < 6; ++db)
                chi[base + db * 16 + l15] = f2bf(o[rb][db][r] * inv);
        }
}

// ---------------------------------------------------------------------------
// Branch 2 (unchanged).
// ---------------------------------------------------------------------------
#define SFS 97

__global__ __launch_bounds__(256) void branch2_v2(const unsigned short* __restrict__ qkbf,
                                                  const float* __restrict__ kpG,
                                                  const float* __restrict__ vpG,
                                                  unsigned short* __restrict__ chi)
{
    __shared__ float qrowS[CDIM];
    __shared__ float SfS[DP * SFS];
    __shared__ float kpS[HN * DP];
    __shared__ float vpS[HN * DP];
    __shared__ float ps[DP][8];
    __shared__ float invs[DP];

    const int tid = threadIdx.x;
    const size_t tok = blockIdx.x;

    if (tid < 192) {
        ushort4 u = *(const ushort4*)&qkbf[tok * CDIM + tid * 4];
        float4 f;
        f.x = bf2f(u.x); f.y = bf2f(u.y); f.z = bf2f(u.z); f.w = bf2f(u.w);
        *(float4*)&qrowS[tid * 4] = f;
    } else {
        int t = tid - 192;
        ((float4*)kpS)[t] = ((const float4*)(kpG + tok * (HN * DP)))[t];
        ((float4*)vpS)[t] = ((const float4*)(vpG + tok * (HN * DP)))[t];
    }
    __syncthreads();

    #pragma unroll
    for (int t = 0; t < 12; ++t) {
        int idx = tid + t * 256;
        int e = idx / DH, d = idx % DH;
        float s = 0.0f;
        #pragma unroll
        for (int h = 0; h < HN; ++h) s += kpS[h * DP + e] * qrowS[h * DH + d];
        SfS[e * SFS + d] = exp2f(s * 1.44269504f);
    }
    __syncthreads();

    {
        int e = tid >> 3, g = tid & 7;
        float s = 0.0f;
        #pragma unroll
        for (int j = 0; j < 12; ++j) s += SfS[e * SFS + g * 12 + j];
        ps[e][g] = s;
    }
    __syncthreads();
    if (tid < DP) {
        float s = 0.0f;
        #pragma unroll
        for (int g = 0; g < 8; ++g) s += ps[tid][g];
        invs[tid] = 1.0f / s;
    }
    __syncthreads();
    {
        int h = tid >> 5, e = tid & 31;
        vpS[h * DP + e] *= invs[e];
    }
    __syncthreads();

    #pragma unroll
    for (int t = 0; t < 3; ++t) {
        int c = tid + t * 256;
        int h = c / DH, d = c % DH;
        float s = 0.0f;
        #pragma unroll 8
        for (int e = 0; e < DP; ++e) s += vpS[h * DP + e] * SfS[e * SFS + d];
        size_t idx = tok * CDIM + c;
        chi[idx] = f2bf(bf2f(chi[idx]) + s);
    }
}

// ---------------------------------------------------------------------------
// Launch pipeline (7 launches). Workspace ~82 MB.
// ---------------------------------------------------------------------------
extern "C" void kernel_launch(void* const* d_in, const int* in_sizes, int n_in,
                              void* d_out, int out_size, void* d_ws, size_t ws_size,
                              hipStream_t stream)
{
    (void)in_sizes; (void)n_in; (void)out_size; (void)ws_size;
    const float* x   = (const float*)d_in[0];
    const float* Wqk = (const float*)d_in[1];
    const float* bqk = (const float*)d_in[2];
    const float* Wv  = (const float*)d_in[3];
    const float* bv  = (const float*)d_in[4];
    const float* Wo  = (const float*)d_in[5];
    const float* bo  = (const float*)d_in[6];
    const float* We  = (const float*)d_in[7];
    const float* be  = (const float*)d_in[8];
    const float* Wf  = (const float*)d_in[9];
    const float* bfv = (const float*)d_in[10];
    float* out = (float*)d_out;

    const size_t TE  = (size_t)MTOT * CDIM;     // 6291456
    const size_t WE  = (size_t)CDIM * CDIM;     // 589824
    const size_t WE2 = (size_t)DP * DH;         // 3072
    const size_t PE  = (size_t)MTOT * HN * DP;  // 2097152

    char* p = (char*)d_ws;
    unsigned short* xhi  = (unsigned short*)p;   p += TE * 2;
    unsigned short* qkbf = (unsigned short*)p;   p += TE * 2;
    unsigned short* vbf  = (unsigned short*)p;   p += TE * 2;
    unsigned short* vbft = (unsigned short*)p;   p += TE * 2;
    unsigned short* chi  = (unsigned short*)p;   p += TE * 2;
    unsigned short* wqv  = (unsigned short*)p;   p += 2 * WE * 2;
    unsigned short* woh  = (unsigned short*)p;   p += WE * 2;
    unsigned short* webf = (unsigned short*)p;   p += WE2 * 2;
    unsigned short* wfbf = (unsigned short*)p;   p += WE2 * 2;
    float* kp            = (float*)p;            p += PE * 4;
    float* vp            = (float*)p;            p += PE * 4;

    const int prep_items = TE4 + 3 * WE4 + 2 * WE24;
    prep<<<dim3((prep_items + 255) / 256), 256, 0, stream>>>(
        x, Wqk, Wv, Wo, We, Wf, xhi, wqv, woh, webf, wfbf);

    gemm_qv<<<dim3(2 * CDIM / 128, MTOT / 128), 256, 0, stream>>>(
        xhi, wqv, bqk, bv, qkbf, vbf);

    transpose_v<<<dim3(BSZ * 384), 256, 0, stream>>>(vbf, vbft);

    proj_gemm<<<dim3(MTOT * HN / 128, 2), 256, 0, stream>>>(
        qkbf, vbf, webf, wfbf, be, bfv, kp, vp);

    attn_mfma<<<dim3((NTOK / QT) * BSZ * HN), 256, 0, stream>>>(qkbf, vbft, chi);

    branch2_v2<<<dim3(MTOT), 256, 0, stream>>>(qkbf, kp, vp, chi);

    gemm_out<<<dim3(CDIM / 128, MTOT / 128), 256, 0, stream>>>(chi, woh, bo, out);
}